// Round 7
// baseline (1819.809 us; speedup 1.0000x reference)
//
#include <hip/hip_runtime.h>

// 2-layer tanh RNN (B=4096, T=512, D=30) + MLP head (30->15->15->1), fp32.
//
// One wave per batch chain, block=64 -> 4096 blocks. Per-lane data:
//   x_t   : SGPRs via s_load (wave-uniform address), ping-pong distance 2
//   dk    : Wih1 row r (all lanes)        -> phase 0 (SGPR x operands)
//   aw    : lower=Whh1 row, upper=Wih2 row-> phase 1 (broadcast h1)
//   bw    : lower=W1|W2 rows, upper=Whh2  -> phase 2/3 (broadcast h2/v1)
// Broadcast via v_readlane -> SGPR operand of v_fma. No LDS.
//
// R2-R5 lesson: __launch_bounds__ 2nd arg sets only MIN waves/EU; the backend
// still targets MAX occupancy (512/56~9 waves) and spills everything above
// ~56 VGPRs no matter what. amdgpu_waves_per_eu(3,3) pins the occupancy
// target itself -> RA budget 170 VGPRs, weights stay resident.
// (R6 bench never ran: GPU broker timeout. Identical resubmit.)

namespace {
constexpr int T = 512;
constexpr int D = 30;   // hidden size
constexpr int H = 15;   // head hidden size

// tanh(x) = 1 - 2/(exp(2x)+1): NaN-free at +/-inf, ~1e-6 abs err.
__device__ __forceinline__ float fast_tanh(float x) {
  float e = __expf(2.0f * x);
  return 1.0f - 2.0f * __builtin_amdgcn_rcpf(e + 1.0f);
}

// Broadcast lane `lane`'s value (SGPR result, scalar operand of v_fma).
__device__ __forceinline__ float bcast(float v, int lane) {
  return __int_as_float(__builtin_amdgcn_readlane(__float_as_int(v), lane));
}

// Non-volatile pre-loop pin: value must materialize in an arch VGPR here.
#define PIN(v) asm("" : "+v"(v))

// Uniform-address scalar load: force the value into an SGPR (s_load path).
__device__ __forceinline__ float sload(const float* p) {
  float v = *p;
  asm("" : "+s"(v));
  return v;
}
}  // namespace

__global__ __attribute__((amdgpu_waves_per_eu(3, 3)))
__launch_bounds__(64) void rnn_head_fused(
    const float* __restrict__ x,
    const float* __restrict__ Wih1, const float* __restrict__ Whh1,
    const float* __restrict__ bih1, const float* __restrict__ bhh1,
    const float* __restrict__ Wih2, const float* __restrict__ Whh2,
    const float* __restrict__ bih2, const float* __restrict__ bhh2,
    const float* __restrict__ W1, const float* __restrict__ b1,
    const float* __restrict__ W2, const float* __restrict__ b2,
    const float* __restrict__ W3, const float* __restrict__ b3,
    float* __restrict__ out) {
  const int j = threadIdx.x;           // 0..63
  const bool lo = (j < 32);
  const int ju = j & 31;
  const int r = (ju < D) ? ju : (D - 1);  // clamped row index 0..29

  // ---- per-lane weight rows ----
  float dk[D], aw[D], bw[D];
  {
    const float* Dr = Wih1 + r * D;
    const float* Ar = (lo ? Whh1 : Wih2) + r * D;
#pragma unroll
    for (int k = 0; k < D; ++k) {
      dk[k] = Dr[k];
      aw[k] = Ar[k];
    }
#pragma unroll
    for (int k = 0; k < D; ++k) {
      float v;
      if (!lo)
        v = Whh2[r * D + k];
      else if (j < H)
        v = W1[j * D + k];                 // lanes 0..14: W1 rows (-> v1)
      else if (j >= 16 && j < 31 && k < H)
        v = W2[(j - 16) * H + k];          // lanes 16..30: W2 rows (-> v2)
      else
        v = 0.0f;                          // lanes 15, 31: dead
      bw[k] = v;
    }
  }
#pragma unroll
  for (int k = 0; k < D; ++k) {
    PIN(dk[k]);
    PIN(aw[k]);
    PIN(bw[k]);
  }

  float biasA = lo ? (bih1[r] + bhh1[r]) : (bih2[r] + bhh2[r]);
  float biasB = (j < H) ? b1[j] : ((j >= 16 && j < 31) ? b2[j - 16] : 0.0f);
  const bool mid = (j >= 16) && (j < 31);  // lanes holding v2
  float w3v = mid ? W3[j - 16] : 0.0f;
  const float sb3 = b3[0];
  PIN(biasA);
  PIN(biasB);
  PIN(w3v);

  const float* xr = x + (long)blockIdx.x * (T * D);
  float* outp = out + (long)blockIdx.x * T;

  // x ping-pong in SGPRs (s_load, uniform address), prefetch distance 2.
  float sxA[D], sxB[D];
#pragma unroll
  for (int k = 0; k < D; ++k) sxA[k] = sload(xr + k);
#pragma unroll
  for (int k = 0; k < D; ++k) sxB[k] = sload(xr + D + k);

  float rec1 = 0.0f;  // Whh1*h1_{t-1}, valid on lower lanes
  float rec2 = 0.0f;  // Whh2*h2_{t-1}, valid on upper lanes

  auto step = [&](float(&sx)[D], int tpre) -> float {
    // ---- phase 0: Wih1[r,:] . x_t with SGPR operands (biasA, rec1 folded) --
    float a0 = biasA, a1 = rec1, a2 = 0.0f, a3 = 0.0f;
#pragma unroll
    for (int k = 0; k < D; ++k) {
      if ((k & 3) == 0)
        a0 = fmaf(dk[k], sx[k], a0);
      else if ((k & 3) == 1)
        a1 = fmaf(dk[k], sx[k], a1);
      else if ((k & 3) == 2)
        a2 = fmaf(dk[k], sx[k], a2);
      else
        a3 = fmaf(dk[k], sx[k], a3);
    }
    const float h1 = fast_tanh((a0 + a1) + (a2 + a3));  // lanes 0..29

    // refill this buffer for step tpre (consumed 2 steps from now)
    {
      const float* xn = xr + (long)tpre * D;
#pragma unroll
      for (int k = 0; k < D; ++k) sx[k] = sload(xn + k);
    }

    // ---- phase 1: broadcast h1; lower->rec1_next, upper->layer2 in-proj ----
    float p0 = 0.0f, p1 = 0.0f, p2 = 0.0f, p3 = 0.0f;
#pragma unroll
    for (int k = 0; k < D; ++k) {
      const float s = bcast(h1, k);
      if ((k & 3) == 0)
        p0 = fmaf(aw[k], s, p0);
      else if ((k & 3) == 1)
        p1 = fmaf(aw[k], s, p1);
      else if ((k & 3) == 2)
        p2 = fmaf(aw[k], s, p2);
      else
        p3 = fmaf(aw[k], s, p3);
    }
    const float P1 = (p0 + p1) + (p2 + p3);
    rec1 = P1;                                      // meaningful on lower
    const float h2 = fast_tanh(P1 + biasA + rec2);  // lanes 32..61

    // ---- phase 2: broadcast h2; lower->u1 (b1 folded), upper->rec2_next ----
    float q0 = biasB, q1 = 0.0f, q2 = 0.0f, q3 = 0.0f;  // biasB==0 on upper
#pragma unroll
    for (int k = 0; k < D; ++k) {
      const float s = bcast(h2, 32 + k);
      if ((k & 3) == 0)
        q0 = fmaf(bw[k], s, q0);
      else if ((k & 3) == 1)
        q1 = fmaf(bw[k], s, q1);
      else if ((k & 3) == 2)
        q2 = fmaf(bw[k], s, q2);
      else
        q3 = fmaf(bw[k], s, q3);
    }
    const float P2 = (q0 + q1) + (q2 + q3);
    rec2 = P2;                       // meaningful on upper
    const float v1 = fast_tanh(P2);  // lanes 0..14

    // ---- phase 3: broadcast v1; lanes 16..30 -> u2 (b2 folded) ----
    float u0 = biasB, u1 = 0.0f, u2 = 0.0f, u3 = 0.0f;
#pragma unroll
    for (int k = 0; k < H; ++k) {
      const float s = bcast(v1, k);
      if ((k & 3) == 0)
        u0 = fmaf(bw[k], s, u0);
      else if ((k & 3) == 1)
        u1 = fmaf(bw[k], s, u1);
      else if ((k & 3) == 2)
        u2 = fmaf(bw[k], s, u2);
      else
        u3 = fmaf(bw[k], s, u3);
    }
    const float v2 = fast_tanh((u0 + u1) + (u2 + u3));  // lanes 16..30

    // ---- head layer 3: reduce W3.v2 within the aligned group [16,31] ----
    float pv = mid ? (w3v * v2) : 0.0f;  // cndmask kills garbage-lane values
    pv += __shfl_xor(pv, 8, 16);
    pv += __shfl_xor(pv, 4, 16);
    pv += __shfl_xor(pv, 2, 16);
    pv += __shfl_xor(pv, 1, 16);
    return pv;  // valid on lanes 16..31
  };

  for (int t = 0; t < T; t += 2) {
    const float pA = step(sxA, (t + 2 < T) ? (t + 2) : (T - 1));
    const float pB = step(sxB, (t + 3 < T) ? (t + 3) : (T - 1));
    if (j == 16) {
      float2 o;
      o.x = pA + sb3;
      o.y = pB + sb3;
      *(float2*)(outp + t) = o;  // outp+t is 8B aligned (t even)
    }
  }
}

extern "C" void kernel_launch(void* const* d_in, const int* in_sizes, int n_in,
                              void* d_out, int out_size, void* d_ws,
                              size_t ws_size, hipStream_t stream) {
  const float* x = (const float*)d_in[0];
  const float* Wih1 = (const float*)d_in[1];
  const float* Whh1 = (const float*)d_in[2];
  const float* bih1 = (const float*)d_in[3];
  const float* bhh1 = (const float*)d_in[4];
  const float* Wih2 = (const float*)d_in[5];
  const float* Whh2 = (const float*)d_in[6];
  const float* bih2 = (const float*)d_in[7];
  const float* bhh2 = (const float*)d_in[8];
  const float* W1 = (const float*)d_in[9];
  const float* b1 = (const float*)d_in[10];
  const float* W2 = (const float*)d_in[11];
  const float* b2 = (const float*)d_in[12];
  const float* W3 = (const float*)d_in[13];
  const float* b3 = (const float*)d_in[14];

  const int B = in_sizes[0] / (T * D);  // 4096 chains, one wave each
  dim3 grid(B), block(64);
  hipLaunchKernelGGL(rnn_head_fused, grid, block, 0, stream, x, Wih1, Whh1,
                     bih1, bhh1, Wih2, Whh2, bih2, bhh2, W1, b1, W2, b2, W3, b3,
                     (float*)d_out);
}

// Round 8
// 1248.721 us; speedup vs baseline: 1.4573x; 1.4573x over previous
//
#include <hip/hip_runtime.h>

// 2-layer tanh RNN (B=4096, T=512, D=30) + MLP head (30->15->15->1), fp32.
//
// TWO-PASS: the input projection Wih1*x_t + (bih1+bhh1) is not recurrent, so
// kernel A precomputes xw for all 2.1M (b,t) rows (memory-bound, thread/row,
// weights via uniform s_loads). Kernel B runs the recurrence reading xw.
//
// R2-R7 lesson (gfx950 unified VGPR/AGPR file): the RA parks loop-invariant
// per-lane weights in AGPRs no matter what (VGPR_Count 52-68 while occupancy
// showed total ~150 regs); each use pays v_accvgpr_read. The fix is fewer
// resident weights: dropping Wih1 (30 regs + 65 inst/step) from the
// recurrence cuts total pressure to ~80 <= 128 -> 4 waves/SIMD reachable.
//
// Kernel B layout (R5, minus phase 0): one wave per chain, 4096 blocks.
//   xw_t  : per-lane load (lane r reads xw[b][t][r]), ping-pong distance 2
//   aw    : lower=Whh1 row, upper=Wih2 row -> phase 1 (broadcast h1)
//   bw    : lower=W1|W2 rows, upper=Whh2   -> phase 2/3 (broadcast h2/v1)
// Broadcast via v_readlane -> SGPR operand of v_fma. No LDS.

namespace {
constexpr int T = 512;
constexpr int D = 30;   // hidden size
constexpr int H = 15;   // head hidden size

// tanh(x) = 1 - 2/(exp(2x)+1): NaN-free at +/-inf, ~1e-6 abs err.
__device__ __forceinline__ float fast_tanh(float x) {
  float e = __expf(2.0f * x);
  return 1.0f - 2.0f * __builtin_amdgcn_rcpf(e + 1.0f);
}

// Broadcast lane `lane`'s value (SGPR result, scalar operand of v_fma).
__device__ __forceinline__ float bcast(float v, int lane) {
  return __int_as_float(__builtin_amdgcn_readlane(__float_as_int(v), lane));
}

// Non-volatile pre-loop pin: value must materialize in a register here.
#define PIN(v) asm("" : "+v"(v))
}  // namespace

// ---------------------------------------------------------------------------
// Kernel A: xw[row,:] = Wih1 . x[row,:] + (bih1+bhh1), row = b*T+t.
// Thread per row; weights/biases are uniform -> scalar loads (sL1-hot, 3.6KB).
// Memory-bound: 252 MB read + 252 MB write.
// ---------------------------------------------------------------------------
__global__ __launch_bounds__(256) void xw_precompute(
    const float* __restrict__ x, const float* __restrict__ Wih1,
    const float* __restrict__ bih1, const float* __restrict__ bhh1,
    float* __restrict__ xw) {
  const long row = (long)blockIdx.x * blockDim.x + threadIdx.x;
  const float* xr = x + row * D;

  float xv[D];
#pragma unroll
  for (int k = 0; k < D; k += 2) {  // row*120 is 8B-aligned
    const float2 v = *(const float2*)(xr + k);
    xv[k] = v.x;
    xv[k + 1] = v.y;
  }

  float* op = xw + row * D;
#pragma unroll
  for (int i = 0; i < D; i += 2) {
    float a = bih1[i] + bhh1[i];
    float b = bih1[i + 1] + bhh1[i + 1];
#pragma unroll
    for (int k = 0; k < D; ++k) {
      a = fmaf(Wih1[i * D + k], xv[k], a);
      b = fmaf(Wih1[(i + 1) * D + k], xv[k], b);
    }
    float2 o;
    o.x = a;
    o.y = b;
    *(float2*)(op + i) = o;
  }
}

// ---------------------------------------------------------------------------
// Kernel B: the recurrence + head, reading precomputed xw.
// ---------------------------------------------------------------------------
__global__ __attribute__((amdgpu_waves_per_eu(4, 4)))
__launch_bounds__(64) void rnn_head_rec(
    const float* __restrict__ xw,
    const float* __restrict__ Whh1,
    const float* __restrict__ Wih2, const float* __restrict__ Whh2,
    const float* __restrict__ bih2, const float* __restrict__ bhh2,
    const float* __restrict__ W1, const float* __restrict__ b1,
    const float* __restrict__ W2, const float* __restrict__ b2,
    const float* __restrict__ W3, const float* __restrict__ b3,
    float* __restrict__ out) {
  const int j = threadIdx.x;           // 0..63
  const bool lo = (j < 32);
  const int ju = j & 31;
  const int r = (ju < D) ? ju : (D - 1);  // clamped row index 0..29

  // ---- per-lane weight rows (60 total) ----
  float aw[D], bw[D];
  {
    const float* Ar = (lo ? Whh1 : Wih2) + r * D;
#pragma unroll
    for (int k = 0; k < D; ++k) aw[k] = Ar[k];
#pragma unroll
    for (int k = 0; k < D; ++k) {
      float v;
      if (!lo)
        v = Whh2[r * D + k];
      else if (j < H)
        v = W1[j * D + k];                 // lanes 0..14: W1 rows (-> v1)
      else if (j >= 16 && j < 31 && k < H)
        v = W2[(j - 16) * H + k];          // lanes 16..30: W2 rows (-> v2)
      else
        v = 0.0f;                          // lanes 15, 31: dead
      bw[k] = v;
    }
  }
#pragma unroll
  for (int k = 0; k < D; ++k) {
    PIN(aw[k]);
    PIN(bw[k]);
  }

  // biasA2m: layer-2 bias on upper lanes, 0 on lower (so rec1 stays pure).
  float biasA2m = lo ? 0.0f : (bih2[r] + bhh2[r]);
  // biasB: lanes 0..14 = b1, lanes 16..30 = b2, else 0 (keeps rec2 pure).
  float biasB = (j < H) ? b1[j] : ((j >= 16 && j < 31) ? b2[j - 16] : 0.0f);
  const bool mid = (j >= 16) && (j < 31);  // lanes holding v2
  float w3v = mid ? W3[j - 16] : 0.0f;
  const float sb3 = b3[0];
  PIN(biasA2m);
  PIN(biasB);
  PIN(w3v);

  const float* xr = xw + (long)blockIdx.x * (T * D);
  float* outp = out + (long)blockIdx.x * T;
  const int cj = r;  // per-lane xw slot (clamped; upper lanes mirror lower)

  // xw ping-pong: lane r holds xw_t[r]; prefetch distance 2 (~1000 cyc slack)
  float xvA = xr[cj];      // t = 0
  float xvB = xr[D + cj];  // t = 1

  float rec1 = 0.0f;  // Whh1*h1_{t-1}, valid on lower lanes
  float rec2 = 0.0f;  // Whh2*h2_{t-1}, valid on upper lanes

  auto step = [&](float& xv, int tpre) -> float {
    // xw already holds Wih1.x + bih1 + bhh1
    const float h1 = fast_tanh(xv + rec1);  // valid on lanes 0..29

    // refill this buffer for step tpre (consumed 2 steps from now)
    xv = xr[(long)tpre * D + cj];

    // ---- phase 1: broadcast h1; lower->rec1_next, upper->layer2 preact ----
    float p0 = biasA2m, p1 = 0.0f, p2 = 0.0f, p3 = 0.0f;  // 0 on lower
#pragma unroll
    for (int k = 0; k < D; ++k) {
      const float s = bcast(h1, k);
      if ((k & 3) == 0)
        p0 = fmaf(aw[k], s, p0);
      else if ((k & 3) == 1)
        p1 = fmaf(aw[k], s, p1);
      else if ((k & 3) == 2)
        p2 = fmaf(aw[k], s, p2);
      else
        p3 = fmaf(aw[k], s, p3);
    }
    const float P1 = (p0 + p1) + (p2 + p3);
    rec1 = P1;                                // meaningful on lower (pure dot)
    const float h2 = fast_tanh(P1 + rec2);    // valid on lanes 32..61

    // ---- phase 2: broadcast h2; lower->u1 (b1 folded), upper->rec2_next ----
    float q0 = biasB, q1 = 0.0f, q2 = 0.0f, q3 = 0.0f;  // biasB==0 on upper
#pragma unroll
    for (int k = 0; k < D; ++k) {
      const float s = bcast(h2, 32 + k);
      if ((k & 3) == 0)
        q0 = fmaf(bw[k], s, q0);
      else if ((k & 3) == 1)
        q1 = fmaf(bw[k], s, q1);
      else if ((k & 3) == 2)
        q2 = fmaf(bw[k], s, q2);
      else
        q3 = fmaf(bw[k], s, q3);
    }
    const float P2 = (q0 + q1) + (q2 + q3);
    rec2 = P2;                       // meaningful on upper (pure dot)
    const float v1 = fast_tanh(P2);  // valid on lanes 0..14

    // ---- phase 3: broadcast v1; lanes 16..30 -> u2 (b2 folded) ----
    float u0 = biasB, u1 = 0.0f, u2 = 0.0f, u3 = 0.0f;
#pragma unroll
    for (int k = 0; k < H; ++k) {
      const float s = bcast(v1, k);
      if ((k & 3) == 0)
        u0 = fmaf(bw[k], s, u0);
      else if ((k & 3) == 1)
        u1 = fmaf(bw[k], s, u1);
      else if ((k & 3) == 2)
        u2 = fmaf(bw[k], s, u2);
      else
        u3 = fmaf(bw[k], s, u3);
    }
    const float v2 = fast_tanh((u0 + u1) + (u2 + u3));  // lanes 16..30

    // ---- head layer 3: reduce W3.v2 within the aligned group [16,31] ----
    float pv = mid ? (w3v * v2) : 0.0f;  // cndmask kills garbage-lane values
    pv += __shfl_xor(pv, 8, 16);
    pv += __shfl_xor(pv, 4, 16);
    pv += __shfl_xor(pv, 2, 16);
    pv += __shfl_xor(pv, 1, 16);
    return pv;  // valid on lanes 16..31
  };

  for (int t = 0; t < T; t += 2) {
    const float pA = step(xvA, (t + 2 < T) ? (t + 2) : (T - 1));
    const float pB = step(xvB, (t + 3 < T) ? (t + 3) : (T - 1));
    if (j == 16) {
      float2 o;
      o.x = pA + sb3;
      o.y = pB + sb3;
      *(float2*)(outp + t) = o;  // outp+t is 8B aligned (t even)
    }
  }
}

// ---------------------------------------------------------------------------
// Fallback (ws too small): R5's known-good fused kernel (1070 us).
// ---------------------------------------------------------------------------
__global__ __launch_bounds__(64, 3) void rnn_head_fused_fb(
    const float* __restrict__ x,
    const float* __restrict__ Wih1, const float* __restrict__ Whh1,
    const float* __restrict__ bih1, const float* __restrict__ bhh1,
    const float* __restrict__ Wih2, const float* __restrict__ Whh2,
    const float* __restrict__ bih2, const float* __restrict__ bhh2,
    const float* __restrict__ W1, const float* __restrict__ b1,
    const float* __restrict__ W2, const float* __restrict__ b2,
    const float* __restrict__ W3, const float* __restrict__ b3,
    float* __restrict__ out) {
  const int j = threadIdx.x;
  const bool lo = (j < 32);
  const int ju = j & 31;
  const int r = (ju < D) ? ju : (D - 1);

  float dk[D], aw[D], bw[D];
  {
    const float* Dr = Wih1 + r * D;
    const float* Ar = (lo ? Whh1 : Wih2) + r * D;
#pragma unroll
    for (int k = 0; k < D; ++k) {
      dk[k] = Dr[k];
      aw[k] = Ar[k];
    }
#pragma unroll
    for (int k = 0; k < D; ++k) {
      float v;
      if (!lo)
        v = Whh2[r * D + k];
      else if (j < H)
        v = W1[j * D + k];
      else if (j >= 16 && j < 31 && k < H)
        v = W2[(j - 16) * H + k];
      else
        v = 0.0f;
      bw[k] = v;
    }
  }
#pragma unroll
  for (int k = 0; k < D; ++k) {
    PIN(dk[k]);
    PIN(aw[k]);
    PIN(bw[k]);
  }

  float biasA = lo ? (bih1[r] + bhh1[r]) : (bih2[r] + bhh2[r]);
  float biasB = (j < H) ? b1[j] : ((j >= 16 && j < 31) ? b2[j - 16] : 0.0f);
  const bool mid = (j >= 16) && (j < 31);
  float w3v = mid ? W3[j - 16] : 0.0f;
  const float sb3 = b3[0];
  PIN(biasA);
  PIN(biasB);
  PIN(w3v);

  const float* xr = x + (long)blockIdx.x * (T * D);
  float* outp = out + (long)blockIdx.x * T;
  const int cj = r;

  float xvA = xr[cj];
  float xvB = xr[D + cj];
  float rec1 = 0.0f, rec2 = 0.0f;

  auto step = [&](float& xv, int tpre) -> float {
    float a0 = biasA, a1 = rec1, a2 = 0.0f, a3 = 0.0f;
#pragma unroll
    for (int k = 0; k < D; ++k) {
      const float s = bcast(xv, k);
      if ((k & 3) == 0)
        a0 = fmaf(dk[k], s, a0);
      else if ((k & 3) == 1)
        a1 = fmaf(dk[k], s, a1);
      else if ((k & 3) == 2)
        a2 = fmaf(dk[k], s, a2);
      else
        a3 = fmaf(dk[k], s, a3);
    }
    const float h1 = fast_tanh((a0 + a1) + (a2 + a3));
    xv = xr[(long)tpre * D + cj];

    float p0 = 0.0f, p1 = 0.0f, p2 = 0.0f, p3 = 0.0f;
#pragma unroll
    for (int k = 0; k < D; ++k) {
      const float s = bcast(h1, k);
      if ((k & 3) == 0)
        p0 = fmaf(aw[k], s, p0);
      else if ((k & 3) == 1)
        p1 = fmaf(aw[k], s, p1);
      else if ((k & 3) == 2)
        p2 = fmaf(aw[k], s, p2);
      else
        p3 = fmaf(aw[k], s, p3);
    }
    const float P1 = (p0 + p1) + (p2 + p3);
    rec1 = P1;
    const float h2 = fast_tanh(P1 + biasA + rec2);

    float q0 = biasB, q1 = 0.0f, q2 = 0.0f, q3 = 0.0f;
#pragma unroll
    for (int k = 0; k < D; ++k) {
      const float s = bcast(h2, 32 + k);
      if ((k & 3) == 0)
        q0 = fmaf(bw[k], s, q0);
      else if ((k & 3) == 1)
        q1 = fmaf(bw[k], s, q1);
      else if ((k & 3) == 2)
        q2 = fmaf(bw[k], s, q2);
      else
        q3 = fmaf(bw[k], s, q3);
    }
    const float P2 = (q0 + q1) + (q2 + q3);
    rec2 = P2;
    const float v1 = fast_tanh(P2);

    float u0 = biasB, u1 = 0.0f, u2 = 0.0f, u3 = 0.0f;
#pragma unroll
    for (int k = 0; k < H; ++k) {
      const float s = bcast(v1, k);
      if ((k & 3) == 0)
        u0 = fmaf(bw[k], s, u0);
      else if ((k & 3) == 1)
        u1 = fmaf(bw[k], s, u1);
      else if ((k & 3) == 2)
        u2 = fmaf(bw[k], s, u2);
      else
        u3 = fmaf(bw[k], s, u3);
    }
    const float v2 = fast_tanh((u0 + u1) + (u2 + u3));

    float pv = mid ? (w3v * v2) : 0.0f;
    pv += __shfl_xor(pv, 8, 16);
    pv += __shfl_xor(pv, 4, 16);
    pv += __shfl_xor(pv, 2, 16);
    pv += __shfl_xor(pv, 1, 16);
    return pv;
  };

  for (int t = 0; t < T; t += 2) {
    const float pA = step(xvA, (t + 2 < T) ? (t + 2) : (T - 1));
    const float pB = step(xvB, (t + 3 < T) ? (t + 3) : (T - 1));
    if (j == 16) {
      float2 o;
      o.x = pA + sb3;
      o.y = pB + sb3;
      *(float2*)(outp + t) = o;
    }
  }
}

extern "C" void kernel_launch(void* const* d_in, const int* in_sizes, int n_in,
                              void* d_out, int out_size, void* d_ws,
                              size_t ws_size, hipStream_t stream) {
  const float* x = (const float*)d_in[0];
  const float* Wih1 = (const float*)d_in[1];
  const float* Whh1 = (const float*)d_in[2];
  const float* bih1 = (const float*)d_in[3];
  const float* bhh1 = (const float*)d_in[4];
  const float* Wih2 = (const float*)d_in[5];
  const float* Whh2 = (const float*)d_in[6];
  const float* bih2 = (const float*)d_in[7];
  const float* bhh2 = (const float*)d_in[8];
  const float* W1 = (const float*)d_in[9];
  const float* b1 = (const float*)d_in[10];
  const float* W2 = (const float*)d_in[11];
  const float* b2 = (const float*)d_in[12];
  const float* W3 = (const float*)d_in[13];
  const float* b3 = (const float*)d_in[14];

  const int B = in_sizes[0] / (T * D);         // 4096 chains
  const size_t xw_bytes = (size_t)B * T * D * sizeof(float);  // 252 MB

  if (ws_size >= xw_bytes) {
    float* xw = (float*)d_ws;
    const long rows = (long)B * T;             // 2,097,152
    hipLaunchKernelGGL(xw_precompute, dim3((rows + 255) / 256), dim3(256), 0,
                       stream, x, Wih1, bih1, bhh1, xw);
    hipLaunchKernelGGL(rnn_head_rec, dim3(B), dim3(64), 0, stream, xw, Whh1,
                       Wih2, Whh2, bih2, bhh2, W1, b1, W2, b2, W3, b3,
                       (float*)d_out);
  } else {
    hipLaunchKernelGGL(rnn_head_fused_fb, dim3(B), dim3(64), 0, stream, x,
                       Wih1, Whh1, bih1, bhh1, Wih2, Whh2, bih2, bhh2, W1, b1,
                       W2, b2, W3, b3, (float*)d_out);
  }
}

// Round 9
// 1127.267 us; speedup vs baseline: 1.6144x; 1.1077x over previous
//
#include <hip/hip_runtime.h>

// 2-layer tanh RNN (B=4096, T=512, D=30) + MLP head (30->15->15->1), fp32.
//
// TWO-PASS: kernel A precomputes xw = Wih1*x + (bih1+bhh1) for all 2.1M rows
// (memory-bound); kernel B runs the recurrence + head reading xw.
//
// R8 lessons:
//  - A was 4x off roofline (1.15 TB/s): 120B-strided per-row float2 IO is
//    VMEM-transaction-bound. Fix: LDS-staged coalesced loads/stores.
//  - B ran 408 inst/step vs ~203 ideal; bloat ~ #weights + ~2/readlane ->
//    VALU-writes-SGPR -> VALU-reads-SGPR hazard between each v_readlane and
//    its consuming v_fma. Fix: batch all readlanes of a phase into SGPRs,
//    sched_barrier(0), then the FMA batch (SGPRs are stale by then).

namespace {
constexpr int T = 512;
constexpr int D = 30;   // hidden size
constexpr int H = 15;   // head hidden size

// tanh(x) = 1 - 2/(exp(2x)+1): NaN-free at +/-inf, ~1e-6 abs err.
__device__ __forceinline__ float fast_tanh(float x) {
  float e = __expf(2.0f * x);
  return 1.0f - 2.0f * __builtin_amdgcn_rcpf(e + 1.0f);
}

// Broadcast lane `lane`'s value (SGPR result, scalar operand of v_fma).
__device__ __forceinline__ float bcast(float v, int lane) {
  return __int_as_float(__builtin_amdgcn_readlane(__float_as_int(v), lane));
}

// Non-volatile pre-loop pin: value must materialize in a register here.
#define PIN(v) asm("" : "+v"(v))
}  // namespace

// ---------------------------------------------------------------------------
// Kernel A: xw[row,:] = Wih1 . x[row,:] + (bih1+bhh1), row = b*T+t.
// 256 rows/block. Coalesced IO through an LDS tile (stride-31 pad: 31*t+k
// mod 32 is distinct across a wave -> conflict-free row reads).
// ---------------------------------------------------------------------------
__global__ __launch_bounds__(256) void xw_precompute(
    const float* __restrict__ x, const float* __restrict__ Wih1,
    const float* __restrict__ bih1, const float* __restrict__ bhh1,
    float* __restrict__ xw) {
  __shared__ float xs[256 * 31];
  const int tid = threadIdx.x;
  const long base = (long)blockIdx.x * (256 * 30);  // tile element offset

  // stage in: 15 x coalesced float2 (wave reads 512B contiguous per iter)
#pragma unroll
  for (int k = 0; k < 15; ++k) {
    const int idx = k * 512 + tid * 2;       // even -> col even, col+1 same row
    const float2 v = *(const float2*)(x + base + idx);
    const int row = idx / 30;                // magic-mul
    const int col = idx - row * 30;
    xs[row * 31 + col] = v.x;
    xs[row * 31 + col + 1] = v.y;
  }
  __syncthreads();

  // compute: thread t owns row t (conflict-free LDS reads)
  float xv[D];
#pragma unroll
  for (int k = 0; k < D; ++k) xv[k] = xs[tid * 31 + k];
#pragma unroll
  for (int i = 0; i < D; ++i) {
    float a = bih1[i] + bhh1[i];             // uniform -> s_load
#pragma unroll
    for (int k = 0; k < D; ++k) a = fmaf(Wih1[i * D + k], xv[k], a);
    xs[tid * 31 + i] = a;                    // own-row writeback (no race)
  }
  __syncthreads();

  // stage out: coalesced float2 stores
#pragma unroll
  for (int k = 0; k < 15; ++k) {
    const int idx = k * 512 + tid * 2;
    const int row = idx / 30;
    const int col = idx - row * 30;
    float2 o;
    o.x = xs[row * 31 + col];
    o.y = xs[row * 31 + col + 1];
    *(float2*)(xw + base + idx) = o;
  }
}

// ---------------------------------------------------------------------------
// Kernel B: the recurrence + head, reading precomputed xw.
// One wave per chain, 4096 blocks. Phase pattern: batched readlanes -> SGPRs,
// sched_barrier, then the FMA batch (no SGPR-hazard stalls).
// ---------------------------------------------------------------------------
__global__ __attribute__((amdgpu_waves_per_eu(4, 4)))
__launch_bounds__(64) void rnn_head_rec(
    const float* __restrict__ xw,
    const float* __restrict__ Whh1,
    const float* __restrict__ Wih2, const float* __restrict__ Whh2,
    const float* __restrict__ bih2, const float* __restrict__ bhh2,
    const float* __restrict__ W1, const float* __restrict__ b1,
    const float* __restrict__ W2, const float* __restrict__ b2,
    const float* __restrict__ W3, const float* __restrict__ b3,
    float* __restrict__ out) {
  const int j = threadIdx.x;           // 0..63
  const bool lo = (j < 32);
  const int ju = j & 31;
  const int r = (ju < D) ? ju : (D - 1);  // clamped row index 0..29

  // ---- per-lane weight rows (60 total) ----
  float aw[D], bw[D];
  {
    const float* Ar = (lo ? Whh1 : Wih2) + r * D;
#pragma unroll
    for (int k = 0; k < D; ++k) aw[k] = Ar[k];
#pragma unroll
    for (int k = 0; k < D; ++k) {
      float v;
      if (!lo)
        v = Whh2[r * D + k];
      else if (j < H)
        v = W1[j * D + k];                 // lanes 0..14: W1 rows (-> v1)
      else if (j >= 16 && j < 31 && k < H)
        v = W2[(j - 16) * H + k];          // lanes 16..30: W2 rows (-> v2)
      else
        v = 0.0f;                          // lanes 15, 31: dead
      bw[k] = v;
    }
  }
#pragma unroll
  for (int k = 0; k < D; ++k) {
    PIN(aw[k]);
    PIN(bw[k]);
  }

  // biasA2m: layer-2 bias on upper lanes, 0 on lower (so rec1 stays pure).
  float biasA2m = lo ? 0.0f : (bih2[r] + bhh2[r]);
  // biasB: lanes 0..14 = b1, lanes 16..30 = b2, else 0 (keeps rec2 pure).
  float biasB = (j < H) ? b1[j] : ((j >= 16 && j < 31) ? b2[j - 16] : 0.0f);
  const bool mid = (j >= 16) && (j < 31);  // lanes holding v2
  float w3v = mid ? W3[j - 16] : 0.0f;
  const float sb3 = b3[0];
  PIN(biasA2m);
  PIN(biasB);
  PIN(w3v);

  const float* xr = xw + (long)blockIdx.x * (T * D);
  float* outp = out + (long)blockIdx.x * T;
  const int cj = r;  // per-lane xw slot (clamped; upper lanes mirror lower)

  // xw ping-pong: lane r holds xw_t[r]; prefetch distance 2 (~1000 cyc slack)
  float xvA = xr[cj];      // t = 0
  float xvB = xr[D + cj];  // t = 1

  float rec1 = 0.0f;  // Whh1*h1_{t-1}, valid on lower lanes
  float rec2 = 0.0f;  // Whh2*h2_{t-1}, valid on upper lanes

  auto step = [&](float& xv, int tpre) -> float {
    // xw already holds Wih1.x + bih1 + bhh1
    const float h1 = fast_tanh(xv + rec1);  // valid on lanes 0..29

    // refill this buffer for step tpre (consumed 2 steps from now)
    xv = xr[(long)tpre * D + cj];

    // ---- phase 1: broadcast h1; lower->rec1_next, upper->layer2 preact ----
    float s1[D];
#pragma unroll
    for (int k = 0; k < D; ++k) s1[k] = bcast(h1, k);
    __builtin_amdgcn_sched_barrier(0);
    float p0 = biasA2m, p1 = 0.0f, p2 = 0.0f, p3 = 0.0f;  // 0 on lower
#pragma unroll
    for (int k = 0; k < D; ++k) {
      if ((k & 3) == 0)
        p0 = fmaf(aw[k], s1[k], p0);
      else if ((k & 3) == 1)
        p1 = fmaf(aw[k], s1[k], p1);
      else if ((k & 3) == 2)
        p2 = fmaf(aw[k], s1[k], p2);
      else
        p3 = fmaf(aw[k], s1[k], p3);
    }
    const float P1 = (p0 + p1) + (p2 + p3);
    rec1 = P1;                                // meaningful on lower (pure dot)
    const float h2 = fast_tanh(P1 + rec2);    // valid on lanes 32..61

    // ---- phase 2: broadcast h2; lower->u1 (b1 folded), upper->rec2_next ----
    float s2[D];
#pragma unroll
    for (int k = 0; k < D; ++k) s2[k] = bcast(h2, 32 + k);
    __builtin_amdgcn_sched_barrier(0);
    float q0 = biasB, q1 = 0.0f, q2 = 0.0f, q3 = 0.0f;  // biasB==0 on upper
#pragma unroll
    for (int k = 0; k < D; ++k) {
      if ((k & 3) == 0)
        q0 = fmaf(bw[k], s2[k], q0);
      else if ((k & 3) == 1)
        q1 = fmaf(bw[k], s2[k], q1);
      else if ((k & 3) == 2)
        q2 = fmaf(bw[k], s2[k], q2);
      else
        q3 = fmaf(bw[k], s2[k], q3);
    }
    const float P2 = (q0 + q1) + (q2 + q3);
    rec2 = P2;                       // meaningful on upper (pure dot)
    const float v1 = fast_tanh(P2);  // valid on lanes 0..14

    // ---- phase 3: broadcast v1; lanes 16..30 -> u2 (b2 folded) ----
    float s3[H];
#pragma unroll
    for (int k = 0; k < H; ++k) s3[k] = bcast(v1, k);
    __builtin_amdgcn_sched_barrier(0);
    float u0 = biasB, u1 = 0.0f, u2 = 0.0f, u3 = 0.0f;
#pragma unroll
    for (int k = 0; k < H; ++k) {
      if ((k & 3) == 0)
        u0 = fmaf(bw[k], s3[k], u0);
      else if ((k & 3) == 1)
        u1 = fmaf(bw[k], s3[k], u1);
      else if ((k & 3) == 2)
        u2 = fmaf(bw[k], s3[k], u2);
      else
        u3 = fmaf(bw[k], s3[k], u3);
    }
    const float v2 = fast_tanh((u0 + u1) + (u2 + u3));  // lanes 16..30

    // ---- head layer 3: reduce W3.v2 within the aligned group [16,31] ----
    float pv = mid ? (w3v * v2) : 0.0f;  // cndmask kills garbage-lane values
    pv += __shfl_xor(pv, 8, 16);
    pv += __shfl_xor(pv, 4, 16);
    pv += __shfl_xor(pv, 2, 16);
    pv += __shfl_xor(pv, 1, 16);
    return pv;  // valid on lanes 16..31
  };

  for (int t = 0; t < T; t += 2) {
    const float pA = step(xvA, (t + 2 < T) ? (t + 2) : (T - 1));
    const float pB = step(xvB, (t + 3 < T) ? (t + 3) : (T - 1));
    if (j == 16) {
      float2 o;
      o.x = pA + sb3;
      o.y = pB + sb3;
      *(float2*)(outp + t) = o;  // outp+t is 8B aligned (t even)
    }
  }
}

// ---------------------------------------------------------------------------
// Fallback (ws too small): R5's known-good fused kernel (1070 us).
// ---------------------------------------------------------------------------
__global__ __launch_bounds__(64, 3) void rnn_head_fused_fb(
    const float* __restrict__ x,
    const float* __restrict__ Wih1, const float* __restrict__ Whh1,
    const float* __restrict__ bih1, const float* __restrict__ bhh1,
    const float* __restrict__ Wih2, const float* __restrict__ Whh2,
    const float* __restrict__ bih2, const float* __restrict__ bhh2,
    const float* __restrict__ W1, const float* __restrict__ b1,
    const float* __restrict__ W2, const float* __restrict__ b2,
    const float* __restrict__ W3, const float* __restrict__ b3,
    float* __restrict__ out) {
  const int j = threadIdx.x;
  const bool lo = (j < 32);
  const int ju = j & 31;
  const int r = (ju < D) ? ju : (D - 1);

  float dk[D], aw[D], bw[D];
  {
    const float* Dr = Wih1 + r * D;
    const float* Ar = (lo ? Whh1 : Wih2) + r * D;
#pragma unroll
    for (int k = 0; k < D; ++k) {
      dk[k] = Dr[k];
      aw[k] = Ar[k];
    }
#pragma unroll
    for (int k = 0; k < D; ++k) {
      float v;
      if (!lo)
        v = Whh2[r * D + k];
      else if (j < H)
        v = W1[j * D + k];
      else if (j >= 16 && j < 31 && k < H)
        v = W2[(j - 16) * H + k];
      else
        v = 0.0f;
      bw[k] = v;
    }
  }
#pragma unroll
  for (int k = 0; k < D; ++k) {
    PIN(dk[k]);
    PIN(aw[k]);
    PIN(bw[k]);
  }

  float biasA = lo ? (bih1[r] + bhh1[r]) : (bih2[r] + bhh2[r]);
  float biasB = (j < H) ? b1[j] : ((j >= 16 && j < 31) ? b2[j - 16] : 0.0f);
  const bool mid = (j >= 16) && (j < 31);
  float w3v = mid ? W3[j - 16] : 0.0f;
  const float sb3 = b3[0];
  PIN(biasA);
  PIN(biasB);
  PIN(w3v);

  const float* xr = x + (long)blockIdx.x * (T * D);
  float* outp = out + (long)blockIdx.x * T;
  const int cj = r;

  float xvA = xr[cj];
  float xvB = xr[D + cj];
  float rec1 = 0.0f, rec2 = 0.0f;

  auto step = [&](float& xv, int tpre) -> float {
    float a0 = biasA, a1 = rec1, a2 = 0.0f, a3 = 0.0f;
#pragma unroll
    for (int k = 0; k < D; ++k) {
      const float s = bcast(xv, k);
      if ((k & 3) == 0)
        a0 = fmaf(dk[k], s, a0);
      else if ((k & 3) == 1)
        a1 = fmaf(dk[k], s, a1);
      else if ((k & 3) == 2)
        a2 = fmaf(dk[k], s, a2);
      else
        a3 = fmaf(dk[k], s, a3);
    }
    const float h1 = fast_tanh((a0 + a1) + (a2 + a3));
    xv = xr[(long)tpre * D + cj];

    float p0 = 0.0f, p1 = 0.0f, p2 = 0.0f, p3 = 0.0f;
#pragma unroll
    for (int k = 0; k < D; ++k) {
      const float s = bcast(h1, k);
      if ((k & 3) == 0)
        p0 = fmaf(aw[k], s, p0);
      else if ((k & 3) == 1)
        p1 = fmaf(aw[k], s, p1);
      else if ((k & 3) == 2)
        p2 = fmaf(aw[k], s, p2);
      else
        p3 = fmaf(aw[k], s, p3);
    }
    const float P1 = (p0 + p1) + (p2 + p3);
    rec1 = P1;
    const float h2 = fast_tanh(P1 + biasA + rec2);

    float q0 = biasB, q1 = 0.0f, q2 = 0.0f, q3 = 0.0f;
#pragma unroll
    for (int k = 0; k < D; ++k) {
      const float s = bcast(h2, 32 + k);
      if ((k & 3) == 0)
        q0 = fmaf(bw[k], s, q0);
      else if ((k & 3) == 1)
        q1 = fmaf(bw[k], s, q1);
      else if ((k & 3) == 2)
        q2 = fmaf(bw[k], s, q2);
      else
        q3 = fmaf(bw[k], s, q3);
    }
    const float P2 = (q0 + q1) + (q2 + q3);
    rec2 = P2;
    const float v1 = fast_tanh(P2);

    float u0 = biasB, u1 = 0.0f, u2 = 0.0f, u3 = 0.0f;
#pragma unroll
    for (int k = 0; k < H; ++k) {
      const float s = bcast(v1, k);
      if ((k & 3) == 0)
        u0 = fmaf(bw[k], s, u0);
      else if ((k & 3) == 1)
        u1 = fmaf(bw[k], s, u1);
      else if ((k & 3) == 2)
        u2 = fmaf(bw[k], s, u2);
      else
        u3 = fmaf(bw[k], s, u3);
    }
    const float v2 = fast_tanh((u0 + u1) + (u2 + u3));

    float pv = mid ? (w3v * v2) : 0.0f;
    pv += __shfl_xor(pv, 8, 16);
    pv += __shfl_xor(pv, 4, 16);
    pv += __shfl_xor(pv, 2, 16);
    pv += __shfl_xor(pv, 1, 16);
    return pv;
  };

  for (int t = 0; t < T; t += 2) {
    const float pA = step(xvA, (t + 2 < T) ? (t + 2) : (T - 1));
    const float pB = step(xvB, (t + 3 < T) ? (t + 3) : (T - 1));
    if (j == 16) {
      float2 o;
      o.x = pA + sb3;
      o.y = pB + sb3;
      *(float2*)(outp + t) = o;
    }
  }
}

extern "C" void kernel_launch(void* const* d_in, const int* in_sizes, int n_in,
                              void* d_out, int out_size, void* d_ws,
                              size_t ws_size, hipStream_t stream) {
  const float* x = (const float*)d_in[0];
  const float* Wih1 = (const float*)d_in[1];
  const float* Whh1 = (const float*)d_in[2];
  const float* bih1 = (const float*)d_in[3];
  const float* bhh1 = (const float*)d_in[4];
  const float* Wih2 = (const float*)d_in[5];
  const float* Whh2 = (const float*)d_in[6];
  const float* bih2 = (const float*)d_in[7];
  const float* bhh2 = (const float*)d_in[8];
  const float* W1 = (const float*)d_in[9];
  const float* b1 = (const float*)d_in[10];
  const float* W2 = (const float*)d_in[11];
  const float* b2 = (const float*)d_in[12];
  const float* W3 = (const float*)d_in[13];
  const float* b3 = (const float*)d_in[14];

  const int B = in_sizes[0] / (T * D);         // 4096 chains
  const size_t xw_bytes = (size_t)B * T * D * sizeof(float);  // 252 MB

  if (ws_size >= xw_bytes) {
    float* xw = (float*)d_ws;
    const long rows = (long)B * T;             // 2,097,152 = 8192 * 256
    hipLaunchKernelGGL(xw_precompute, dim3(rows / 256), dim3(256), 0, stream,
                       x, Wih1, bih1, bhh1, xw);
    hipLaunchKernelGGL(rnn_head_rec, dim3(B), dim3(64), 0, stream, xw, Whh1,
                       Wih2, Whh2, bih2, bhh2, W1, b1, W2, b2, W3, b3,
                       (float*)d_out);
  } else {
    hipLaunchKernelGGL(rnn_head_fused_fb, dim3(B), dim3(64), 0, stream, x,
                       Wih1, Whh1, bih1, bhh1, Wih2, Whh2, bih2, bhh2, W1, b1,
                       W2, b2, W3, b3, (float*)d_out);
  }
}